// Round 4
// baseline (785.648 us; speedup 1.0000x reference)
//
#include <hip/hip_runtime.h>
#include <hip/hip_bf16.h>

#define NPTS 8192
#define KN   32
#define DIM  256
#define DH   128
#define DOUT 512

typedef __attribute__((ext_vector_type(8))) short bf16x8;
typedef __attribute__((ext_vector_type(4))) short short4v;
typedef __attribute__((ext_vector_type(4))) float f32x4;

#define MFMA16(a, b, c) __builtin_amdgcn_mfma_f32_16x16x32_bf16((a), (b), (c), 0, 0, 0)

__device__ __forceinline__ short f2b(float f) {
    __hip_bfloat16 h = __float2bfloat16(f);
    return *reinterpret_cast<short*>(&h);
}

// ---------------- ws layout (bytes) ----------------
#define WSO_QATTN 0u                      // float[8192*256]
#define WSO_RES   8388608u                // float[8192*256]
#define WSO_WKT   16777216u               // short[65536]  -WkT[o][i]  (negated!)
#define WSO_WVT   16908288u               // short[65536]
#define WSO_G1T   17039360u               // short[65536]
#define WSO_G2T   17170432u               // short[65536]
#define WSO_D2T   17301504u               // short[32768]  d2T[o=256][i=128]
#define WSO_OWT   17367040u               // short[131072] owT[o=512][i=256]

// ========= prep 1: weights -> bf16 transposed, LDS tile transpose (coalesced) ====
// 104 blocks: [0,64) = Wk/Wv/g1/g2 (16 tiles each of 64x64), [64,72) = d2w,
// [72,104) = ow. dst[o][i] = src[i][o].
extern "C" __global__ __launch_bounds__(256)
void prep_w(const float* __restrict__ Wk, const float* __restrict__ Wv,
            const float* __restrict__ g1w, const float* __restrict__ g2w,
            const float* __restrict__ d2w, const float* __restrict__ ow,
            short* __restrict__ wkT, short* __restrict__ wvT,
            short* __restrict__ g1T, short* __restrict__ g2T,
            short* __restrict__ d2T, short* __restrict__ owT)
{
    __shared__ float s_t[64][65];
    const int bid = blockIdx.x, t = threadIdx.x;
    const float* src; short* dst;
    int scols, dcols, O, I;
    bool neg = false;
    if (bid < 64) {
        const int mat = bid >> 4, tile = bid & 15;
        O = (tile >> 2) * 64; I = (tile & 3) * 64;
        scols = 256; dcols = 256;
        if (mat == 0)      { src = Wk;  dst = wkT; neg = true; }
        else if (mat == 1) { src = Wv;  dst = wvT; }
        else if (mat == 2) { src = g1w; dst = g1T; }
        else               { src = g2w; dst = g2T; }
    } else if (bid < 72) {
        const int tile = bid - 64;
        O = (tile >> 1) * 64; I = (tile & 1) * 64;
        src = d2w; dst = d2T; scols = 256; dcols = 128;
    } else {
        const int tile = bid - 72;
        O = (tile >> 2) * 64; I = (tile & 3) * 64;
        src = ow; dst = owT; scols = 512; dcols = 256;
    }
    #pragma unroll
    for (int rep = 0; rep < 16; ++rep) {
        const int lin = rep * 256 + t;
        s_t[lin >> 6][lin & 63] =
            src[(size_t)(I + (lin >> 6)) * scols + O + (lin & 63)];
    }
    __syncthreads();
    #pragma unroll
    for (int rep = 0; rep < 16; ++rep) {
        const int lin = rep * 256 + t;
        const int o = lin >> 6, i = lin & 63;
        float v = s_t[i][o];
        if (neg) v = -v;
        dst[(size_t)(O + o) * dcols + I + i] = f2b(v);
    }
}

// ================= prep 2: q_attn = feats_q @ Wq (fp32), 32 rows/block ==========
extern "C" __global__ __launch_bounds__(256)
void prep_q(const float* __restrict__ feats_q, const float* __restrict__ Wq,
            const float* __restrict__ xyz_q, float* __restrict__ q_attn,
            float* __restrict__ out)
{
    const int b = blockIdx.x;
    const int t = threadIdx.x;
    if (b >= 256) {                        // 96 blocks: xyz passthrough
        const int idx = (b - 256) * 256 + t;
        out[idx] = xyz_q[idx];
        return;
    }
    __shared__ float s_q[32][256];
    for (int j = 0; j < 32; ++j)
        s_q[j][t] = feats_q[(size_t)(b * 32 + j) * 256 + t];
    __syncthreads();
    float acc[32];
    #pragma unroll
    for (int pt = 0; pt < 32; ++pt) acc[pt] = 0.f;
    for (int k = 0; k < 256; k += 4) {
        float wv0 = Wq[(k + 0) * 256 + t];
        float wv1 = Wq[(k + 1) * 256 + t];
        float wv2 = Wq[(k + 2) * 256 + t];
        float wv3 = Wq[(k + 3) * 256 + t];
        #pragma unroll
        for (int pt = 0; pt < 32; ++pt) {
            const float4 sv = *(const float4*)&s_q[pt][k];
            acc[pt] = fmaf(sv.x, wv0, acc[pt]);
            acc[pt] = fmaf(sv.y, wv1, acc[pt]);
            acc[pt] = fmaf(sv.z, wv2, acc[pt]);
            acc[pt] = fmaf(sv.w, wv3, acc[pt]);
        }
    }
    #pragma unroll
    for (int pt = 0; pt < 32; ++pt)
        q_attn[(size_t)(b * 32 + pt) * 256 + t] = acc[pt];
}

// ====== main: 2 points/block, 8 waves (512 thr), M=64, N=32/wave, 2 blocks/CU ===
// LDS (49152 B): F/H shorts [0,16384)  : feats full-K 64x256, later h/t 64x256
//                R1  shorts [16384,24576): r1 64x128
// XOR swizzle: elem = row*LD + (c ^ ((row&7)<<3))
extern "C" __global__ __launch_bounds__(512, 4)
void ctb_main(const float* __restrict__ xyz_q, const float* __restrict__ xyz_kv,
              const float* __restrict__ feats_kv,
              const float* __restrict__ d1w, const float* __restrict__ d1b,
              const float* __restrict__ d2b, const float* __restrict__ g1b,
              const float* __restrict__ g2b,
              const float* __restrict__ q_attn,
              const short* __restrict__ wkTn, const short* __restrict__ wvT,
              const short* __restrict__ g1T, const short* __restrict__ g2T,
              const short* __restrict__ d2T,
              float* __restrict__ res_ws)
{
    extern __shared__ short s_lds[];
    const int t    = threadIdx.x;
    const int w    = t >> 6;       // 0..7
    const int lane = t & 63;
    const int q    = lane >> 4;
    const int ln   = lane & 15;
    const int p0   = blockIdx.x * 2;
    const int colbase = 32 * w + ln;

    // ---------- stage feats (full K=256, 64 rows) + r1 (cooperative) ----------
    {
        const int srow = t >> 3;   // 0..63
        const int sc   = t & 7;    // 0..7
        const float* fp = feats_kv + ((size_t)p0 * KN + srow) * DIM + sc * 32;
        #pragma unroll
        for (int j = 0; j < 8; ++j) {
            const float4 v = *(const float4*)(fp + 4 * j);
            const int c = sc * 32 + 4 * j;
            short4v sv;
            sv[0] = f2b(v.x); sv[1] = f2b(v.y); sv[2] = f2b(v.z); sv[3] = f2b(v.w);
            *(short4v*)&s_lds[srow * 256 + (c ^ ((srow & 7) << 3))] = sv;
        }
        const int pt = srow >> 5;
        const float qx = xyz_q[(p0 + pt) * 3 + 0];
        const float qy = xyz_q[(p0 + pt) * 3 + 1];
        const float qz = xyz_q[(p0 + pt) * 3 + 2];
        const float* xk = xyz_kv + ((size_t)p0 * KN + srow) * 3;
        const float rx = qx - xk[0], ry = qy - xk[1], rz = qz - xk[2];
        #pragma unroll
        for (int j = 0; j < 16; ++j) {
            const int c = sc * 16 + j;
            const float v = fmaxf(fmaf(rx, d1w[c],
                                  fmaf(ry, d1w[DH + c],
                                  fmaf(rz, d1w[2 * DH + c], d1b[c]))), 0.f);
            s_lds[16384 + srow * 128 + (c ^ ((srow & 7) << 3))] = f2b(v);
        }
    }
    __syncthreads();

    // ---------- phase 1: vp = d2b + pos + v ; h = pos + q - k -> H ----------
    f32x4 vp[4][2];
    #pragma unroll
    for (int nt = 0; nt < 2; ++nt) {
        const float bb = d2b[colbase + 16 * nt];
        #pragma unroll
        for (int mt = 0; mt < 4; ++mt) vp[mt][nt] = (f32x4){bb, bb, bb, bb};
    }
    #pragma unroll
    for (int ks = 0; ks < 4; ++ks) {                 // pos: K=128, A from R1
        bf16x8 ar[4];
        #pragma unroll
        for (int mt = 0; mt < 4; ++mt) {
            const int row = 16 * mt + ln;
            ar[mt] = *(const bf16x8*)&s_lds[16384 + row * 128 +
                                            ((32 * ks + 8 * q) ^ ((row & 7) << 3))];
        }
        #pragma unroll
        for (int nt = 0; nt < 2; ++nt) {
            const bf16x8 bb = *(const bf16x8*)(d2T + (colbase + 16 * nt) * DH +
                                               32 * ks + 8 * q);
            #pragma unroll
            for (int mt = 0; mt < 4; ++mt) vp[mt][nt] = MFMA16(ar[mt], bb, vp[mt][nt]);
        }
    }
    f32x4 hacc[4][2];                                // h starts from pos + q_attn
    {
        float qv[2][2];
        #pragma unroll
        for (int pt = 0; pt < 2; ++pt)
            #pragma unroll
            for (int nt = 0; nt < 2; ++nt)
                qv[pt][nt] = q_attn[(size_t)(p0 + pt) * DIM + colbase + 16 * nt];
        #pragma unroll
        for (int mt = 0; mt < 4; ++mt)
            #pragma unroll
            for (int nt = 0; nt < 2; ++nt)
                #pragma unroll
                for (int r = 0; r < 4; ++r)
                    hacc[mt][nt][r] = vp[mt][nt][r] + qv[mt >> 1][nt];
    }
    #pragma unroll
    for (int ks = 0; ks < 8; ++ks) {                 // kv: K=256 (full, staged)
        bf16x8 af[4];
        #pragma unroll
        for (int mt = 0; mt < 4; ++mt) {
            const int row = 16 * mt + ln;
            af[mt] = *(const bf16x8*)&s_lds[row * 256 +
                                            ((32 * ks + 8 * q) ^ ((row & 7) << 3))];
        }
        #pragma unroll
        for (int nt = 0; nt < 2; ++nt) {
            const int co = (colbase + 16 * nt) * DIM + 32 * ks + 8 * q;
            const bf16x8 bk = *(const bf16x8*)(wkTn + co);
            const bf16x8 bv = *(const bf16x8*)(wvT + co);
            #pragma unroll
            for (int mt = 0; mt < 4; ++mt) {
                hacc[mt][nt] = MFMA16(af[mt], bk, hacc[mt][nt]);
                vp[mt][nt]   = MFMA16(af[mt], bv, vp[mt][nt]);
            }
        }
    }
    __syncthreads();                                 // F fully consumed
    #pragma unroll
    for (int mt = 0; mt < 4; ++mt)                   // h -> H (overlays F)
        #pragma unroll
        for (int nt = 0; nt < 2; ++nt)
            #pragma unroll
            for (int r = 0; r < 4; ++r) {
                const int row = 16 * mt + 4 * q + r;
                const int col = colbase + 16 * nt;
                s_lds[row * 256 + (col ^ ((row & 7) << 3))] = f2b(hacc[mt][nt][r]);
            }
    __syncthreads();

    // ---------- phase 2: t = relu(h @ g1 + g1b) -> H (in place) ----------
    {
        f32x4 tacc[4][2];
        #pragma unroll
        for (int nt = 0; nt < 2; ++nt) {
            const float bb = g1b[colbase + 16 * nt];
            #pragma unroll
            for (int mt = 0; mt < 4; ++mt) tacc[mt][nt] = (f32x4){bb, bb, bb, bb};
        }
        #pragma unroll
        for (int ks = 0; ks < 8; ++ks) {
            bf16x8 ah[4];
            #pragma unroll
            for (int mt = 0; mt < 4; ++mt) {
                const int row = 16 * mt + ln;
                ah[mt] = *(const bf16x8*)&s_lds[row * 256 +
                                                ((32 * ks + 8 * q) ^ ((row & 7) << 3))];
            }
            #pragma unroll
            for (int nt = 0; nt < 2; ++nt) {
                const bf16x8 bb = *(const bf16x8*)(g1T + (colbase + 16 * nt) * DIM +
                                                   32 * ks + 8 * q);
                #pragma unroll
                for (int mt = 0; mt < 4; ++mt)
                    tacc[mt][nt] = MFMA16(ah[mt], bb, tacc[mt][nt]);
            }
        }
        __syncthreads();                             // all reads of h done
        #pragma unroll
        for (int mt = 0; mt < 4; ++mt)
            #pragma unroll
            for (int nt = 0; nt < 2; ++nt)
                #pragma unroll
                for (int r = 0; r < 4; ++r) {
                    const int row = 16 * mt + 4 * q + r;
                    const int col = colbase + 16 * nt;
                    s_lds[row * 256 + (col ^ ((row & 7) << 3))] =
                        f2b(fmaxf(tacc[mt][nt][r], 0.f));
                }
        __syncthreads();
    }

    // ---------- phase 3: ap = t@g2+g2b -> softmax_k -> res = sum ap*vp ----------
    {
        f32x4 ap[4][2];
        #pragma unroll
        for (int nt = 0; nt < 2; ++nt) {
            const float bb = g2b[colbase + 16 * nt];
            #pragma unroll
            for (int mt = 0; mt < 4; ++mt) ap[mt][nt] = (f32x4){bb, bb, bb, bb};
        }
        #pragma unroll
        for (int ks = 0; ks < 8; ++ks) {
            bf16x8 at[4];
            #pragma unroll
            for (int mt = 0; mt < 4; ++mt) {
                const int row = 16 * mt + ln;
                at[mt] = *(const bf16x8*)&s_lds[row * 256 +
                                                ((32 * ks + 8 * q) ^ ((row & 7) << 3))];
            }
            #pragma unroll
            for (int nt = 0; nt < 2; ++nt) {
                const bf16x8 bb = *(const bf16x8*)(g2T + (colbase + 16 * nt) * DIM +
                                                   32 * ks + 8 * q);
                #pragma unroll
                for (int mt = 0; mt < 4; ++mt)
                    ap[mt][nt] = MFMA16(at[mt], bb, ap[mt][nt]);
            }
        }

        // per-point softmax over 32 neighbors: point pt -> mt tiles {2pt,2pt+1}
        #pragma unroll
        for (int pt = 0; pt < 2; ++pt)
            #pragma unroll
            for (int nt = 0; nt < 2; ++nt) {
                float m = -1e30f;
                #pragma unroll
                for (int m2 = 0; m2 < 2; ++m2)
                    #pragma unroll
                    for (int r = 0; r < 4; ++r)
                        m = fmaxf(m, ap[2 * pt + m2][nt][r]);
                m = fmaxf(m, __shfl_xor(m, 16, 64));
                m = fmaxf(m, __shfl_xor(m, 32, 64));
                float s = 0.f;
                #pragma unroll
                for (int m2 = 0; m2 < 2; ++m2)
                    #pragma unroll
                    for (int r = 0; r < 4; ++r) {
                        const float e = __expf(ap[2 * pt + m2][nt][r] - m);
                        ap[2 * pt + m2][nt][r] = e;
                        s += e;
                    }
                s += __shfl_xor(s, 16, 64);
                s += __shfl_xor(s, 32, 64);
                float racc = 0.f;
                #pragma unroll
                for (int m2 = 0; m2 < 2; ++m2)
                    #pragma unroll
                    for (int r = 0; r < 4; ++r)
                        racc = fmaf(ap[2 * pt + m2][nt][r], vp[2 * pt + m2][nt][r],
                                    racc);
                racc += __shfl_xor(racc, 16, 64);
                racc += __shfl_xor(racc, 32, 64);
                if (q == 0)
                    res_ws[(size_t)(p0 + pt) * DIM + colbase + 16 * nt] = racc / s;
            }
    }
}

// ================= out: res @ out_w + out_b (MFMA), 32 rows/block ===============
extern "C" __global__ __launch_bounds__(256, 2)
void ctb_out(const float* __restrict__ res_ws, const short* __restrict__ owT,
             const float* __restrict__ ob, float* __restrict__ out)
{
    __shared__ __align__(16) short s_a[32][264];
    const int t = threadIdx.x, w = t >> 6, lane = t & 63, q = lane >> 4, ln = lane & 15;
    const int rowbase = blockIdx.x * 32;

    {   // stage res rows -> bf16 LDS
        const int row = t >> 3;
        const int c0  = (t & 7) * 32;
        const float* src = res_ws + (size_t)(rowbase + row) * DIM + c0;
        #pragma unroll
        for (int j = 0; j < 32; j += 4) {
            const float4 v = *(const float4*)(src + j);
            s_a[row][c0 + j + 0] = f2b(v.x);
            s_a[row][c0 + j + 1] = f2b(v.y);
            s_a[row][c0 + j + 2] = f2b(v.z);
            s_a[row][c0 + j + 3] = f2b(v.w);
        }
    }
    __syncthreads();

    bf16x8 af[2][8];
    #pragma unroll
    for (int mt = 0; mt < 2; ++mt)
        #pragma unroll
        for (int ks = 0; ks < 8; ++ks)
            af[mt][ks] = *(const bf16x8*)&s_a[16 * mt + ln][32 * ks + 8 * q];

    const int colbase = 128 * w + ln;   // wave owns 128 of 512 cols
    f32x4 acc[2][8];
    #pragma unroll
    for (int nt = 0; nt < 8; ++nt) {
        const float bb = ob[colbase + 16 * nt];
        #pragma unroll
        for (int mt = 0; mt < 2; ++mt) acc[mt][nt] = (f32x4){bb, bb, bb, bb};
    }
    #pragma unroll
    for (int ks = 0; ks < 8; ++ks) {
        const short* bp = owT + 32 * ks + 8 * q;
        #pragma unroll
        for (int nt = 0; nt < 8; ++nt) {
            const bf16x8 bb = *(const bf16x8*)(bp + (colbase + 16 * nt) * DIM);
            #pragma unroll
            for (int mt = 0; mt < 2; ++mt)
                acc[mt][nt] = MFMA16(af[mt][ks], bb, acc[mt][nt]);
        }
    }
    float* o = out + (size_t)NPTS * 3;
    #pragma unroll
    for (int mt = 0; mt < 2; ++mt)
        #pragma unroll
        for (int nt = 0; nt < 8; ++nt)
            #pragma unroll
            for (int r = 0; r < 4; ++r) {
                const int row = 16 * mt + 4 * q + r;
                const int col = colbase + 16 * nt;
                o[(size_t)(rowbase + row) * DOUT + col] = acc[mt][nt][r];
            }
}

// ================= launch =================
extern "C" void kernel_launch(void* const* d_in, const int* in_sizes, int n_in,
                              void* d_out, int out_size, void* d_ws, size_t ws_size,
                              hipStream_t stream) {
    const float* xyz_q    = (const float*)d_in[0];
    const float* feats_q  = (const float*)d_in[1];
    const float* xyz_kv   = (const float*)d_in[2];
    const float* feats_kv = (const float*)d_in[3];
    const float* Wq       = (const float*)d_in[4];
    const float* Wk       = (const float*)d_in[5];
    const float* Wv       = (const float*)d_in[6];
    const float* d1w      = (const float*)d_in[7];
    const float* d1b      = (const float*)d_in[8];
    const float* d2w      = (const float*)d_in[9];
    const float* d2b      = (const float*)d_in[10];
    const float* g1w      = (const float*)d_in[11];
    const float* g1b      = (const float*)d_in[12];
    const float* g2w      = (const float*)d_in[13];
    const float* g2b      = (const float*)d_in[14];
    const float* ow       = (const float*)d_in[15];
    const float* ob       = (const float*)d_in[16];
    float* out = (float*)d_out;

    char* ws = (char*)d_ws;
    float* q_attn = (float*)(ws + WSO_QATTN);
    float* res_ws = (float*)(ws + WSO_RES);
    short* wkT    = (short*)(ws + WSO_WKT);
    short* wvT    = (short*)(ws + WSO_WVT);
    short* g1T    = (short*)(ws + WSO_G1T);
    short* g2T    = (short*)(ws + WSO_G2T);
    short* d2T    = (short*)(ws + WSO_D2T);
    short* owT    = (short*)(ws + WSO_OWT);

    prep_w<<<dim3(104), dim3(256), 0, stream>>>(Wk, Wv, g1w, g2w, d2w, ow,
                                                wkT, wvT, g1T, g2T, d2T, owT);
    prep_q<<<dim3(352), dim3(256), 0, stream>>>(feats_q, Wq, xyz_q, q_attn, out);
    ctb_main<<<dim3(4096), dim3(512), 49152, stream>>>(
        xyz_q, xyz_kv, feats_kv, d1w, d1b, d2b, g1b, g2b,
        q_attn, wkT, wvT, g1T, g2T, d2T, res_ws);
    ctb_out<<<dim3(256), dim3(256), 0, stream>>>(res_ws, owT, ob, out);
}

// Round 5
// 682.077 us; speedup vs baseline: 1.1518x; 1.1518x over previous
//
#include <hip/hip_runtime.h>
#include <hip/hip_bf16.h>

#define NPTS 8192
#define KN   32
#define DIM  256
#define DH   128
#define DOUT 512

typedef __attribute__((ext_vector_type(8))) short bf16x8;
typedef __attribute__((ext_vector_type(4))) short short4v;
typedef __attribute__((ext_vector_type(4))) float f32x4;

#define MFMA16(a, b, c) __builtin_amdgcn_mfma_f32_16x16x32_bf16((a), (b), (c), 0, 0, 0)

__device__ __forceinline__ short f2b(float f) {
    __hip_bfloat16 h = __float2bfloat16(f);
    return *reinterpret_cast<short*>(&h);
}

// ---------------- ws layout (bytes) ----------------
#define WSO_QATTN 0u                      // float[8192*256]
#define WSO_RES   8388608u                // float[8192*256]
#define WSO_WKT   16777216u               // short[65536]  -WkT[o][i]  (negated!)
#define WSO_WVT   16908288u               // short[65536]
#define WSO_G1T   17039360u               // short[65536]
#define WSO_G2T   17170432u               // short[65536]
#define WSO_D2T   17301504u               // short[32768]  d2T[o=256][i=128]
#define WSO_OWT   17367040u               // short[131072] owT[o=512][i=256]
#define WSO_WQT   17629184u               // short[65536]  wqT[o=256][i=256]

// ========= prep 1: weights -> bf16 transposed, LDS tile transpose (coalesced) ====
// 120 blocks: [0,64) Wk/Wv/g1/g2, [64,72) d2w, [72,104) ow, [104,120) Wq
extern "C" __global__ __launch_bounds__(256)
void prep_w(const float* __restrict__ Wk, const float* __restrict__ Wv,
            const float* __restrict__ g1w, const float* __restrict__ g2w,
            const float* __restrict__ d2w, const float* __restrict__ ow,
            const float* __restrict__ Wq,
            short* __restrict__ wkT, short* __restrict__ wvT,
            short* __restrict__ g1T, short* __restrict__ g2T,
            short* __restrict__ d2T, short* __restrict__ owT,
            short* __restrict__ wqT)
{
    __shared__ float s_t[64][65];
    const int bid = blockIdx.x, t = threadIdx.x;
    const float* src; short* dst;
    int scols, dcols, O, I;
    bool neg = false;
    if (bid < 64) {
        const int mat = bid >> 4, tile = bid & 15;
        O = (tile >> 2) * 64; I = (tile & 3) * 64;
        scols = 256; dcols = 256;
        if (mat == 0)      { src = Wk;  dst = wkT; neg = true; }
        else if (mat == 1) { src = Wv;  dst = wvT; }
        else if (mat == 2) { src = g1w; dst = g1T; }
        else               { src = g2w; dst = g2T; }
    } else if (bid < 72) {
        const int tile = bid - 64;
        O = (tile >> 1) * 64; I = (tile & 1) * 64;
        src = d2w; dst = d2T; scols = 256; dcols = 128;
    } else if (bid < 104) {
        const int tile = bid - 72;
        O = (tile >> 2) * 64; I = (tile & 3) * 64;
        src = ow; dst = owT; scols = 512; dcols = 256;
    } else {
        const int tile = bid - 104;
        O = (tile >> 2) * 64; I = (tile & 3) * 64;
        src = Wq; dst = wqT; scols = 256; dcols = 256;
    }
    #pragma unroll
    for (int rep = 0; rep < 16; ++rep) {
        const int lin = rep * 256 + t;
        s_t[lin >> 6][lin & 63] =
            src[(size_t)(I + (lin >> 6)) * scols + O + (lin & 63)];
    }
    __syncthreads();
    #pragma unroll
    for (int rep = 0; rep < 16; ++rep) {
        const int lin = rep * 256 + t;
        const int o = lin >> 6, i = lin & 63;
        float v = s_t[i][o];
        if (neg) v = -v;
        dst[(size_t)(O + o) * dcols + I + i] = f2b(v);
    }
}

// ============ prep 2: q_attn = feats_q @ Wq via MFMA, 32 rows/block =============
extern "C" __global__ __launch_bounds__(256)
void prep_q(const float* __restrict__ feats_q, const short* __restrict__ wqT,
            const float* __restrict__ xyz_q, float* __restrict__ q_attn,
            float* __restrict__ out)
{
    const int b = blockIdx.x;
    const int t = threadIdx.x;
    if (b >= 256) {                        // 96 blocks: xyz passthrough
        const int idx = (b - 256) * 256 + t;
        out[idx] = xyz_q[idx];
        return;
    }
    __shared__ __align__(16) short s_a[32][264];
    const int w = t >> 6, lane = t & 63, q = lane >> 4, ln = lane & 15;
    const int rowbase = b * 32;
    {
        const int row = t >> 3;
        const int c0  = (t & 7) * 32;
        const float* src = feats_q + (size_t)(rowbase + row) * DIM + c0;
        #pragma unroll
        for (int j = 0; j < 32; j += 4) {
            const float4 v = *(const float4*)(src + j);
            s_a[row][c0 + j + 0] = f2b(v.x);
            s_a[row][c0 + j + 1] = f2b(v.y);
            s_a[row][c0 + j + 2] = f2b(v.z);
            s_a[row][c0 + j + 3] = f2b(v.w);
        }
    }
    __syncthreads();

    bf16x8 af[2][8];
    #pragma unroll
    for (int mt = 0; mt < 2; ++mt)
        #pragma unroll
        for (int ks = 0; ks < 8; ++ks)
            af[mt][ks] = *(const bf16x8*)&s_a[16 * mt + ln][32 * ks + 8 * q];

    const int colbase = 64 * w + ln;       // wave owns 64 of 256 cols
    f32x4 acc[2][4];
    #pragma unroll
    for (int nt = 0; nt < 4; ++nt)
        #pragma unroll
        for (int mt = 0; mt < 2; ++mt) acc[mt][nt] = (f32x4){0.f, 0.f, 0.f, 0.f};
    #pragma unroll
    for (int ks = 0; ks < 8; ++ks) {
        const short* bp = wqT + 32 * ks + 8 * q;
        #pragma unroll
        for (int nt = 0; nt < 4; ++nt) {
            const bf16x8 bb = *(const bf16x8*)(bp + (colbase + 16 * nt) * DIM);
            #pragma unroll
            for (int mt = 0; mt < 2; ++mt)
                acc[mt][nt] = MFMA16(af[mt][ks], bb, acc[mt][nt]);
        }
    }
    #pragma unroll
    for (int mt = 0; mt < 2; ++mt)
        #pragma unroll
        for (int nt = 0; nt < 4; ++nt)
            #pragma unroll
            for (int r = 0; r < 4; ++r) {
                const int row = 16 * mt + 4 * q + r;
                q_attn[(size_t)(rowbase + row) * DIM + colbase + 16 * nt] =
                    acc[mt][nt][r];
            }
}

// ====== main: 2 points/block, 4 waves (256 thr), M=64, N=64/wave (nt=4) ========
// 2 blocks/CU.  LDS (49152 B):
//   F/H shorts [0,16384)   : feats full-K 64x256, later h/t 64x256 (overlay)
//   R1  shorts [16384,24576): r1 64x128
// XOR swizzle: elem = row*LD + (c ^ ((row&7)<<3))
extern "C" __global__ __launch_bounds__(256, 2)
void ctb_main(const float* __restrict__ xyz_q, const float* __restrict__ xyz_kv,
              const float* __restrict__ feats_kv,
              const float* __restrict__ d1w, const float* __restrict__ d1b,
              const float* __restrict__ d2b, const float* __restrict__ g1b,
              const float* __restrict__ g2b,
              const float* __restrict__ q_attn,
              const short* __restrict__ wkTn, const short* __restrict__ wvT,
              const short* __restrict__ g1T, const short* __restrict__ g2T,
              const short* __restrict__ d2T,
              float* __restrict__ res_ws)
{
    extern __shared__ short s_lds[];
    const int t    = threadIdx.x;
    const int w    = t >> 6;       // 0..3
    const int lane = t & 63;
    const int q    = lane >> 4;
    const int ln   = lane & 15;
    const int p0   = blockIdx.x * 2;
    const int colbase = 64 * w + ln;   // wave owns cols [64w, 64w+64)

    // ---------- stage feats (full K=256, 64 rows) + r1, interleaved b64 ----------
    {
        const int srow = t >> 2;   // 0..63
        const int sc   = t & 3;    // 0..3
        const float* fp = feats_kv + ((size_t)p0 * KN + srow) * DIM;
        #pragma unroll
        for (int j = 0; j < 16; ++j) {
            const int c = 4 * sc + 16 * j;          // interleaved chunks
            const float4 v = *(const float4*)(fp + c);
            short4v sv;
            sv[0] = f2b(v.x); sv[1] = f2b(v.y); sv[2] = f2b(v.z); sv[3] = f2b(v.w);
            *(short4v*)&s_lds[srow * 256 + (c ^ ((srow & 7) << 3))] = sv;
        }
        const int pt = srow >> 5;
        const float qx = xyz_q[(p0 + pt) * 3 + 0];
        const float qy = xyz_q[(p0 + pt) * 3 + 1];
        const float qz = xyz_q[(p0 + pt) * 3 + 2];
        const float* xk = xyz_kv + ((size_t)p0 * KN + srow) * 3;
        const float rx = qx - xk[0], ry = qy - xk[1], rz = qz - xk[2];
        #pragma unroll
        for (int j = 0; j < 8; ++j) {
            const int c = 4 * sc + 16 * j;          // interleaved chunks
            short4v sv;
            #pragma unroll
            for (int e = 0; e < 4; ++e) {
                const int cc = c + e;
                sv[e] = f2b(fmaxf(fmaf(rx, d1w[cc],
                                  fmaf(ry, d1w[DH + cc],
                                  fmaf(rz, d1w[2 * DH + cc], d1b[cc]))), 0.f));
            }
            *(short4v*)&s_lds[16384 + srow * 128 + (c ^ ((srow & 7) << 3))] = sv;
        }
    }
    __syncthreads();

    // ---------- phase 1: vp = d2b + pos + v ; h = pos + q - k -> H ----------
    f32x4 vp[4][4];
    #pragma unroll
    for (int nt = 0; nt < 4; ++nt) {
        const float bb = d2b[colbase + 16 * nt];
        #pragma unroll
        for (int mt = 0; mt < 4; ++mt) vp[mt][nt] = (f32x4){bb, bb, bb, bb};
    }
    #pragma unroll
    for (int ks = 0; ks < 4; ++ks) {                 // pos: K=128, A from R1
        bf16x8 ar[4];
        #pragma unroll
        for (int mt = 0; mt < 4; ++mt) {
            const int row = 16 * mt + ln;
            ar[mt] = *(const bf16x8*)&s_lds[16384 + row * 128 +
                                            ((32 * ks + 8 * q) ^ ((row & 7) << 3))];
        }
        #pragma unroll
        for (int nt = 0; nt < 4; ++nt) {
            const bf16x8 bb = *(const bf16x8*)(d2T + (colbase + 16 * nt) * DH +
                                               32 * ks + 8 * q);
            #pragma unroll
            for (int mt = 0; mt < 4; ++mt) vp[mt][nt] = MFMA16(ar[mt], bb, vp[mt][nt]);
        }
    }
    f32x4 hacc[4][4];                                // h starts from pos + q_attn
    {
        float qv[2][4];
        #pragma unroll
        for (int pt = 0; pt < 2; ++pt)
            #pragma unroll
            for (int nt = 0; nt < 4; ++nt)
                qv[pt][nt] = q_attn[(size_t)(p0 + pt) * DIM + colbase + 16 * nt];
        #pragma unroll
        for (int mt = 0; mt < 4; ++mt)
            #pragma unroll
            for (int nt = 0; nt < 4; ++nt)
                #pragma unroll
                for (int r = 0; r < 4; ++r)
                    hacc[mt][nt][r] = vp[mt][nt][r] + qv[mt >> 1][nt];
    }
    #pragma unroll
    for (int ks = 0; ks < 8; ++ks) {                 // kv: K=256 (full, staged)
        bf16x8 af[4];
        #pragma unroll
        for (int mt = 0; mt < 4; ++mt) {
            const int row = 16 * mt + ln;
            af[mt] = *(const bf16x8*)&s_lds[row * 256 +
                                            ((32 * ks + 8 * q) ^ ((row & 7) << 3))];
        }
        #pragma unroll
        for (int nt = 0; nt < 4; ++nt) {
            const int co = (colbase + 16 * nt) * DIM + 32 * ks + 8 * q;
            const bf16x8 bk = *(const bf16x8*)(wkTn + co);
            const bf16x8 bv = *(const bf16x8*)(wvT + co);
            #pragma unroll
            for (int mt = 0; mt < 4; ++mt) {
                hacc[mt][nt] = MFMA16(af[mt], bk, hacc[mt][nt]);
                vp[mt][nt]   = MFMA16(af[mt], bv, vp[mt][nt]);
            }
        }
    }
    __syncthreads();                                 // F fully consumed
    #pragma unroll
    for (int mt = 0; mt < 4; ++mt)                   // h -> H (overlays F)
        #pragma unroll
        for (int nt = 0; nt < 4; ++nt)
            #pragma unroll
            for (int r = 0; r < 4; ++r) {
                const int row = 16 * mt + 4 * q + r;
                const int col = colbase + 16 * nt;
                s_lds[row * 256 + (col ^ ((row & 7) << 3))] = f2b(hacc[mt][nt][r]);
            }
    __syncthreads();

    // ---------- phase 2: t = relu(h @ g1 + g1b) -> H (in place) ----------
    {
        f32x4 tacc[4][4];
        #pragma unroll
        for (int nt = 0; nt < 4; ++nt) {
            const float bb = g1b[colbase + 16 * nt];
            #pragma unroll
            for (int mt = 0; mt < 4; ++mt) tacc[mt][nt] = (f32x4){bb, bb, bb, bb};
        }
        #pragma unroll
        for (int ks = 0; ks < 8; ++ks) {
            bf16x8 ah[4];
            #pragma unroll
            for (int mt = 0; mt < 4; ++mt) {
                const int row = 16 * mt + ln;
                ah[mt] = *(const bf16x8*)&s_lds[row * 256 +
                                                ((32 * ks + 8 * q) ^ ((row & 7) << 3))];
            }
            #pragma unroll
            for (int nt = 0; nt < 4; ++nt) {
                const bf16x8 bb = *(const bf16x8*)(g1T + (colbase + 16 * nt) * DIM +
                                                   32 * ks + 8 * q);
                #pragma unroll
                for (int mt = 0; mt < 4; ++mt)
                    tacc[mt][nt] = MFMA16(ah[mt], bb, tacc[mt][nt]);
            }
        }
        __syncthreads();                             // all reads of h done
        #pragma unroll
        for (int mt = 0; mt < 4; ++mt)
            #pragma unroll
            for (int nt = 0; nt < 4; ++nt)
                #pragma unroll
                for (int r = 0; r < 4; ++r) {
                    const int row = 16 * mt + 4 * q + r;
                    const int col = colbase + 16 * nt;
                    s_lds[row * 256 + (col ^ ((row & 7) << 3))] =
                        f2b(fmaxf(tacc[mt][nt][r], 0.f));
                }
        __syncthreads();
    }

    // ---------- phase 3: ap = t@g2+g2b -> softmax_k -> res = sum ap*vp ----------
    {
        f32x4 ap[4][4];
        #pragma unroll
        for (int nt = 0; nt < 4; ++nt) {
            const float bb = g2b[colbase + 16 * nt];
            #pragma unroll
            for (int mt = 0; mt < 4; ++mt) ap[mt][nt] = (f32x4){bb, bb, bb, bb};
        }
        #pragma unroll
        for (int ks = 0; ks < 8; ++ks) {
            bf16x8 at[4];
            #pragma unroll
            for (int mt = 0; mt < 4; ++mt) {
                const int row = 16 * mt + ln;
                at[mt] = *(const bf16x8*)&s_lds[row * 256 +
                                                ((32 * ks + 8 * q) ^ ((row & 7) << 3))];
            }
            #pragma unroll
            for (int nt = 0; nt < 4; ++nt) {
                const bf16x8 bb = *(const bf16x8*)(g2T + (colbase + 16 * nt) * DIM +
                                                   32 * ks + 8 * q);
                #pragma unroll
                for (int mt = 0; mt < 4; ++mt)
                    ap[mt][nt] = MFMA16(at[mt], bb, ap[mt][nt]);
            }
        }

        // per-point softmax over 32 neighbors: point pt -> mt tiles {2pt,2pt+1}
        #pragma unroll
        for (int pt = 0; pt < 2; ++pt)
            #pragma unroll
            for (int nt = 0; nt < 4; ++nt) {
                float m = -1e30f;
                #pragma unroll
                for (int m2 = 0; m2 < 2; ++m2)
                    #pragma unroll
                    for (int r = 0; r < 4; ++r)
                        m = fmaxf(m, ap[2 * pt + m2][nt][r]);
                m = fmaxf(m, __shfl_xor(m, 16, 64));
                m = fmaxf(m, __shfl_xor(m, 32, 64));
                float s = 0.f;
                #pragma unroll
                for (int m2 = 0; m2 < 2; ++m2)
                    #pragma unroll
                    for (int r = 0; r < 4; ++r) {
                        const float e = __expf(ap[2 * pt + m2][nt][r] - m);
                        ap[2 * pt + m2][nt][r] = e;
                        s += e;
                    }
                s += __shfl_xor(s, 16, 64);
                s += __shfl_xor(s, 32, 64);
                float racc = 0.f;
                #pragma unroll
                for (int m2 = 0; m2 < 2; ++m2)
                    #pragma unroll
                    for (int r = 0; r < 4; ++r)
                        racc = fmaf(ap[2 * pt + m2][nt][r], vp[2 * pt + m2][nt][r],
                                    racc);
                racc += __shfl_xor(racc, 16, 64);
                racc += __shfl_xor(racc, 32, 64);
                if (q == 0)
                    res_ws[(size_t)(p0 + pt) * DIM + colbase + 16 * nt] = racc / s;
            }
    }
}

// ================= out: res @ out_w + out_b (MFMA), 32 rows/block ===============
extern "C" __global__ __launch_bounds__(256, 2)
void ctb_out(const float* __restrict__ res_ws, const short* __restrict__ owT,
             const float* __restrict__ ob, float* __restrict__ out)
{
    __shared__ __align__(16) short s_a[32][264];
    const int t = threadIdx.x, w = t >> 6, lane = t & 63, q = lane >> 4, ln = lane & 15;
    const int rowbase = blockIdx.x * 32;

    {   // stage res rows -> bf16 LDS
        const int row = t >> 3;
        const int c0  = (t & 7) * 32;
        const float* src = res_ws + (size_t)(rowbase + row) * DIM + c0;
        #pragma unroll
        for (int j = 0; j < 32; j += 4) {
            const float4 v = *(const float4*)(src + j);
            s_a[row][c0 + j + 0] = f2b(v.x);
            s_a[row][c0 + j + 1] = f2b(v.y);
            s_a[row][c0 + j + 2] = f2b(v.z);
            s_a[row][c0 + j + 3] = f2b(v.w);
        }
    }
    __syncthreads();

    bf16x8 af[2][8];
    #pragma unroll
    for (int mt = 0; mt < 2; ++mt)
        #pragma unroll
        for (int ks = 0; ks < 8; ++ks)
            af[mt][ks] = *(const bf16x8*)&s_a[16 * mt + ln][32 * ks + 8 * q];

    const int colbase = 128 * w + ln;   // wave owns 128 of 512 cols
    f32x4 acc[2][8];
    #pragma unroll
    for (int nt = 0; nt < 8; ++nt) {
        const float bb = ob[colbase + 16 * nt];
        #pragma unroll
        for (int mt = 0; mt < 2; ++mt) acc[mt][nt] = (f32x4){bb, bb, bb, bb};
    }
    #pragma unroll
    for (int ks = 0; ks < 8; ++ks) {
        const short* bp = owT + 32 * ks + 8 * q;
        #pragma unroll
        for (int nt = 0; nt < 8; ++nt) {
            const bf16x8 bb = *(const bf16x8*)(bp + (colbase + 16 * nt) * DIM);
            #pragma unroll
            for (int mt = 0; mt < 2; ++mt)
                acc[mt][nt] = MFMA16(af[mt][ks], bb, acc[mt][nt]);
        }
    }
    float* o = out + (size_t)NPTS * 3;
    #pragma unroll
    for (int mt = 0; mt < 2; ++mt)
        #pragma unroll
        for (int nt = 0; nt < 8; ++nt)
            #pragma unroll
            for (int r = 0; r < 4; ++r) {
                const int row = 16 * mt + 4 * q + r;
                const int col = colbase + 16 * nt;
                o[(size_t)(rowbase + row) * DOUT + col] = acc[mt][nt][r];
            }
}

// ================= launch =================
extern "C" void kernel_launch(void* const* d_in, const int* in_sizes, int n_in,
                              void* d_out, int out_size, void* d_ws, size_t ws_size,
                              hipStream_t stream) {
    const float* xyz_q    = (const float*)d_in[0];
    const float* feats_q  = (const float*)d_in[1];
    const float* xyz_kv   = (const float*)d_in[2];
    const float* feats_kv = (const float*)d_in[3];
    const float* Wq       = (const float*)d_in[4];
    const float* Wk       = (const float*)d_in[5];
    const float* Wv       = (const float*)d_in[6];
    const float* d1w      = (const float*)d_in[7];
    const float* d1b      = (const float*)d_in[8];
    const float* d2w      = (const float*)d_in[9];
    const float* d2b      = (const float*)d_in[10];
    const float* g1w      = (const float*)d_in[11];
    const float* g1b      = (const float*)d_in[12];
    const float* g2w      = (const float*)d_in[13];
    const float* g2b      = (const float*)d_in[14];
    const float* ow       = (const float*)d_in[15];
    const float* ob       = (const float*)d_in[16];
    float* out = (float*)d_out;

    char* ws = (char*)d_ws;
    float* q_attn = (float*)(ws + WSO_QATTN);
    float* res_ws = (float*)(ws + WSO_RES);
    short* wkT    = (short*)(ws + WSO_WKT);
    short* wvT    = (short*)(ws + WSO_WVT);
    short* g1T    = (short*)(ws + WSO_G1T);
    short* g2T    = (short*)(ws + WSO_G2T);
    short* d2T    = (short*)(ws + WSO_D2T);
    short* owT    = (short*)(ws + WSO_OWT);
    short* wqT    = (short*)(ws + WSO_WQT);

    prep_w<<<dim3(120), dim3(256), 0, stream>>>(Wk, Wv, g1w, g2w, d2w, ow, Wq,
                                                wkT, wvT, g1T, g2T, d2T, owT, wqT);
    prep_q<<<dim3(352), dim3(256), 0, stream>>>(feats_q, wqT, xyz_q, q_attn, out);
    ctb_main<<<dim3(4096), dim3(256), 49152, stream>>>(
        xyz_q, xyz_kv, feats_kv, d1w, d1b, d2b, g1b, g2b,
        q_attn, wkT, wvT, g1T, g2T, d2T, res_ws);
    ctb_out<<<dim3(256), dim3(256), 0, stream>>>(res_ws, owT, ob, out);
}